// Round 5
// baseline (462.345 us; speedup 1.0000x reference)
//
#include <hip/hip_runtime.h>

#define FA 75
#define FB 12
#define CC 100
#define NN 20000
#define EE 40000
#define GG 1000
#define BN_EPS 1e-5f
#define XPAD 76   // x rows padded to 76 floats -> 304 B, 16-B aligned

// msg tiling
#define MSG_THREADS 512        // 8 waves
#define MSG_EDGES   512        // edges per block
#define MSG_CH      10         // channels per block (10 groups cover C=100)

// workspace layout (float offsets)
#define OFF_W1P   0          // packed W1+b1: 7500 rows * 16 floats = 120000
#define OFF_S     0          // S[C,G] = 100000, reuses W1p region AFTER msg
#define OFF_XP    120000     // padded x [N][76] = 1,520,000
#define OFF_AGGT  1640000    // aggT [C, N] = 2,000,000
#define OFF_HT    3640000    // h_t  [C, N] = 2,000,000
#define OFF_STAT  5640000    // sacc[100] (sum) + sacc2[100] (sumsq)
#define OFF_START 5640200    // int start[G+1]

// prep: (a) pack W1+b1 into 16-float rows, (b) molecule start offsets,
// (c) pad-pack x into 76-float (16B-aligned) rows for float4 gathers.
__global__ __launch_bounds__(256) void prep_kernel(
    const float* __restrict__ W1, const float* __restrict__ b1,
    const float* __restrict__ x, const int* __restrict__ batch,
    float* __restrict__ W1p, float* __restrict__ xp, int* __restrict__ start)
{
    int idx = blockIdx.x * 256 + threadIdx.x;
    if (idx < 120000) {
        int r = idx >> 4, k = idx & 15;
        float v = 0.f;
        if (k < 12) v = W1[k * 7500 + r];
        else if (k == 12) v = b1[r];
        W1p[idx] = v;
    } else if (idx < 140000) {
        int n = idx - 120000;
        int b = batch[n];
        int prev = (n == 0) ? -1 : batch[n - 1];
        for (int g = prev + 1; g <= b; ++g) start[g] = n;
        if (n == NN - 1)
            for (int g = b + 1; g <= GG; ++g) start[g] = NN;
    } else {
        int t = idx - 140000;
        if (t < NN * XPAD) {
            int n = t / XPAD;
            int i = t - n * XPAD;
            xp[t] = (i < FA) ? x[n * FA + i] : 0.f;
        }
    }
}

// Fused NNConv message + scatter, LDS-staged weights.
// Block: 512 thr (8 waves) = 512 edges x 10 channels. The 75x10 weight slice
// (13 useful floats per (i,c)) is staged once into LDS (~39 KB) and read via
// wave-uniform broadcast ds_read_b128 in the K-loop -> no scalar-pipe stalls.
// grid = ceil(E/512) * 10, blockIdx = eb*10 + cg (same-edge blocks adjacent).
__global__ __launch_bounds__(MSG_THREADS, 6) void msg_kernel(
    const float* __restrict__ xp, const float* __restrict__ edge_attr,
    const float* __restrict__ W1p, const int* __restrict__ eidx,
    float* __restrict__ aggT)
{
    __shared__ float4 w0s[FA * MSG_CH];
    __shared__ float4 w1s[FA * MSG_CH];
    __shared__ float4 w2s[FA * MSG_CH];
    __shared__ float  bbs[FA * MSG_CH];

    const int eb = blockIdx.x / MSG_CH;
    const int cg = blockIdx.x - eb * MSG_CH;           // 0..9
    const int cbase = cg * MSG_CH;

    // cooperative stage: 750 rows x 4 quarters of the 16-float W1p rows
    for (int t = threadIdx.x; t < FA * MSG_CH * 4; t += MSG_THREADS) {
        int r = t >> 2, q = t & 3;
        int i = r / MSG_CH, j = r - i * MSG_CH;
        const float4 v = *(const float4*)(W1p + ((size_t)(i * CC + cbase + j)) * 16 + q * 4);
        if (q == 0) w0s[r] = v;
        else if (q == 1) w1s[r] = v;
        else if (q == 2) w2s[r] = v;
        else bbs[r] = v.x;   // b1
    }
    __syncthreads();

    const int e = eb * MSG_EDGES + threadIdx.x;
    const bool ok = (e < EE);
    const int ec = ok ? e : (EE - 1);
    const int src = eidx[ec];
    const int dst = eidx[EE + ec];

    const float4* ea4 = (const float4*)(edge_attr + (size_t)ec * FB);
    float4 a0 = ea4[0], a1 = ea4[1], a2 = ea4[2];

    const float4* xr4 = (const float4*)(xp + (size_t)src * XPAD);

    float acc[MSG_CH];
#pragma unroll
    for (int j = 0; j < MSG_CH; ++j) acc[j] = 0.f;

    float4 cur = xr4[0];
#pragma unroll 1
    for (int k = 0; k < 18; ++k) {
        float4 nxt = xr4[k + 1];                       // prefetch next x chunk
        float xiv[4] = {cur.x, cur.y, cur.z, cur.w};
#pragma unroll
        for (int u = 0; u < 4; ++u) {
            const int base = (k * 4 + u) * MSG_CH;
#pragma unroll
            for (int j = 0; j < MSG_CH; ++j) {
                float4 w0 = w0s[base + j];
                float4 w1 = w1s[base + j];
                float4 w2 = w2s[base + j];
                float z = bbs[base + j];
                z = fmaf(a0.x, w0.x, z);
                z = fmaf(a0.y, w0.y, z);
                z = fmaf(a0.z, w0.z, z);
                z = fmaf(a0.w, w0.w, z);
                z = fmaf(a1.x, w1.x, z);
                z = fmaf(a1.y, w1.y, z);
                z = fmaf(a1.z, w1.z, z);
                z = fmaf(a1.w, w1.w, z);
                z = fmaf(a2.x, w2.x, z);
                z = fmaf(a2.y, w2.y, z);
                z = fmaf(a2.z, w2.z, z);
                z = fmaf(a2.w, w2.w, z);
                z = fmaxf(z, 0.f);
                acc[j] = fmaf(xiv[u], z, acc[j]);
            }
        }
        cur = nxt;
    }
    {   // tail: i = 72, 73, 74
        float xiv[3] = {cur.x, cur.y, cur.z};
#pragma unroll
        for (int u = 0; u < 3; ++u) {
            const int base = (72 + u) * MSG_CH;
#pragma unroll
            for (int j = 0; j < MSG_CH; ++j) {
                float4 w0 = w0s[base + j];
                float4 w1 = w1s[base + j];
                float4 w2 = w2s[base + j];
                float z = bbs[base + j];
                z = fmaf(a0.x, w0.x, z);
                z = fmaf(a0.y, w0.y, z);
                z = fmaf(a0.z, w0.z, z);
                z = fmaf(a0.w, w0.w, z);
                z = fmaf(a1.x, w1.x, z);
                z = fmaf(a1.y, w1.y, z);
                z = fmaf(a1.z, w1.z, z);
                z = fmaf(a1.w, w1.w, z);
                z = fmaf(a2.x, w2.x, z);
                z = fmaf(a2.y, w2.y, z);
                z = fmaf(a2.z, w2.z, z);
                z = fmaf(a2.w, w2.w, z);
                z = fmaxf(z, 0.f);
                acc[j] = fmaf(xiv[u], z, acc[j]);
            }
        }
    }

    if (ok) {
#pragma unroll
        for (int j = 0; j < MSG_CH; ++j)
            atomicAdd(&aggT[(size_t)(cbase + j) * NN + dst], acc[j]);
    }
}

// h_t[c][n] = relu(x @ W_root + aggT + bias), channel-transposed.
__global__ __launch_bounds__(128) void root_kernel(
    const float* __restrict__ xp, const float* __restrict__ W_root,
    const float* __restrict__ bias, const float* __restrict__ aggT,
    float* __restrict__ h_t)
{
    const int lane = threadIdx.x & 63;
    const int w = threadIdx.x >> 6;                    // 0..1
    const int nb = blockIdx.x / 5;
    const int cg = (blockIdx.x - nb * 5) * 2 + w;      // 0..9
    const int cbase = __builtin_amdgcn_readfirstlane(cg * 10);
    const int n = nb * 64 + lane;
    const bool ok = (n < NN);
    const int nc = ok ? n : NN - 1;
    const float4* xr4 = (const float4*)(xp + (size_t)nc * XPAD);

    float acc[10];
#pragma unroll
    for (int j = 0; j < 10; ++j) acc[j] = 0.f;

    float4 cur = xr4[0];
#pragma unroll 1
    for (int k = 0; k < 18; ++k) {
        float4 nxt = xr4[k + 1];
        float xiv[4] = {cur.x, cur.y, cur.z, cur.w};
#pragma unroll
        for (int u = 0; u < 4; ++u) {
            const float* wrow = W_root + (k * 4 + u) * CC + cbase;  // s_load
#pragma unroll
            for (int j = 0; j < 10; ++j) acc[j] = fmaf(xiv[u], wrow[j], acc[j]);
        }
        cur = nxt;
    }
    {
        float xiv[3] = {cur.x, cur.y, cur.z};
#pragma unroll
        for (int u = 0; u < 3; ++u) {
            const float* wrow = W_root + (72 + u) * CC + cbase;
#pragma unroll
            for (int j = 0; j < 10; ++j) acc[j] = fmaf(xiv[u], wrow[j], acc[j]);
        }
    }

    if (ok) {
#pragma unroll
        for (int j = 0; j < 10; ++j) {
            size_t off = (size_t)(cbase + j) * NN + n;
            h_t[off] = fmaxf(acc[j] + bias[cbase + j] + aggT[off], 0.f);
        }
    }
}

// partial per-channel sums: grid = C * 5 slabs; float atomics into sacc.
__global__ __launch_bounds__(256) void stats_part_kernel(
    const float* __restrict__ h_t, float* __restrict__ sacc)
{
    const int c = blockIdx.x / 5;
    const int slab = blockIdx.x - c * 5;
    const float4* row = (const float4*)(h_t + (size_t)c * NN) + slab * 1000;
    double s = 0.0, s2 = 0.0;
    for (int k = threadIdx.x; k < 1000; k += 256) {
        float4 v = row[k];
        s += (double)v.x + (double)v.y + (double)v.z + (double)v.w;
        s2 += (double)v.x * v.x + (double)v.y * v.y
            + (double)v.z * v.z + (double)v.w * v.w;
    }
    __shared__ double sh[256];
    __shared__ double sh2[256];
    sh[threadIdx.x] = s;
    sh2[threadIdx.x] = s2;
    __syncthreads();
    for (int o = 128; o > 0; o >>= 1) {
        if (threadIdx.x < o) {
            sh[threadIdx.x] += sh[threadIdx.x + o];
            sh2[threadIdx.x] += sh2[threadIdx.x + o];
        }
        __syncthreads();
    }
    if (threadIdx.x == 0) {
        atomicAdd(&sacc[c], (float)sh[0]);
        atomicAdd(&sacc[CC + c], (float)sh2[0]);
    }
}

// raw per-(g,c) pool sums (BN folded in algebraically in out_kernel)
__global__ __launch_bounds__(256) void pool_kernel(
    const float* __restrict__ h_t, const int* __restrict__ start,
    float* __restrict__ S)
{
    int t = blockIdx.x * 256 + threadIdx.x;
    if (t >= CC * GG) return;
    int c = t / GG;
    int g = t - c * GG;
    const float* col = h_t + (size_t)c * NN;
    int n1 = start[g + 1];
    float s = 0.f;
    for (int n = start[g]; n < n1; ++n) s += col[n];
    S[t] = s;
}

// out[g] = relu(A_c*S[c,g] + cnt_g*(beta_c - A_c*mean_c)) . W_out + b_out
__global__ __launch_bounds__(128) void out_kernel(
    const float* __restrict__ S, const float* __restrict__ sacc,
    const float* __restrict__ gamma, const float* __restrict__ beta,
    const int* __restrict__ start, const float* __restrict__ W_out,
    const float* __restrict__ b_out, float* __restrict__ out)
{
    const int g = blockIdx.x;
    const int c = threadIdx.x;
    float v = 0.f;
    if (c < CC) {
        float mean = sacc[c] / NN;
        float var = sacc[CC + c] / NN - mean * mean;
        float rstd = rsqrtf(var + BN_EPS);
        float A = gamma[c] * rstd;
        float B = beta[c] - A * mean;
        float cnt = (float)(start[g + 1] - start[g]);
        float pooled = fmaf(A, S[(size_t)c * GG + g], cnt * B);
        v = fmaxf(pooled, 0.f) * W_out[c];
    }
    __shared__ float sh[128];
    sh[threadIdx.x] = v;
    __syncthreads();
    for (int o = 64; o > 0; o >>= 1) {
        if (threadIdx.x < o) sh[threadIdx.x] += sh[threadIdx.x + o];
        __syncthreads();
    }
    if (threadIdx.x == 0) out[g] = sh[0] + b_out[0];
}

extern "C" void kernel_launch(void* const* d_in, const int* in_sizes, int n_in,
                              void* d_out, int out_size, void* d_ws, size_t ws_size,
                              hipStream_t stream)
{
    const float* x         = (const float*)d_in[0];
    const float* edge_attr = (const float*)d_in[1];
    const float* W1        = (const float*)d_in[2];
    const float* b1        = (const float*)d_in[3];
    const float* W_root    = (const float*)d_in[4];
    const float* bias      = (const float*)d_in[5];
    const float* gamma     = (const float*)d_in[6];
    const float* beta      = (const float*)d_in[7];
    const float* W_out     = (const float*)d_in[8];
    const float* b_out     = (const float*)d_in[9];
    const int*   eidx      = (const int*)d_in[10];
    const int*   batch     = (const int*)d_in[11];

    float* ws    = (float*)d_ws;
    float* W1p   = ws + OFF_W1P;
    float* S     = ws + OFF_S;      // aliases W1p; used only after msg
    float* xp    = ws + OFF_XP;
    float* aggT  = ws + OFF_AGGT;
    float* h_t   = ws + OFF_HT;
    float* sacc  = ws + OFF_STAT;
    int*   start = (int*)(ws + OFF_START);
    float* out   = (float*)d_out;

    hipMemsetAsync(aggT, 0, (size_t)NN * CC * sizeof(float), stream);
    hipMemsetAsync(sacc, 0, 2 * CC * sizeof(float), stream);

    {
        int total = 140000 + NN * XPAD;
        prep_kernel<<<(total + 255) / 256, 256, 0, stream>>>(
            W1, b1, x, batch, W1p, xp, start);
    }
    {
        int eblocks = (EE + MSG_EDGES - 1) / MSG_EDGES;   // 79
        msg_kernel<<<eblocks * MSG_CH, MSG_THREADS, 0, stream>>>(
            xp, edge_attr, W1p, eidx, aggT);
    }
    root_kernel<<<((NN + 63) / 64) * 5, 128, 0, stream>>>(xp, W_root, bias, aggT, h_t);
    stats_part_kernel<<<CC * 5, 256, 0, stream>>>(h_t, sacc);
    pool_kernel<<<(CC * GG + 255) / 256, 256, 0, stream>>>(h_t, start, S);
    out_kernel<<<GG, 128, 0, stream>>>(S, sacc, gamma, beta, start, W_out, b_out, out);
}